// Round 18
// baseline (144.788 us; speedup 1.0000x reference)
//
#include <hip/hip_runtime.h>
#include <math.h>

typedef _Float16 f16x8 __attribute__((ext_vector_type(8)));
typedef float    f32x4 __attribute__((ext_vector_type(4)));

static __device__ __forceinline__ unsigned short f2h(float f) {
  _Float16 h = (_Float16)f;                       // RNE
  return __builtin_bit_cast(unsigned short, h);
}
// packed f16 helpers (VOP3P)
static __device__ __forceinline__ unsigned int pk_max(unsigned int a, unsigned int b) {
  unsigned int d;
  asm("v_pk_max_f16 %0, %1, %2" : "=v"(d) : "v"(a), "v"(b));
  return d;
}
static __device__ __forceinline__ unsigned int pk_add(unsigned int a, unsigned int b) {
  unsigned int d;
  asm("v_pk_add_f16 %0, %1, %2" : "=v"(d) : "v"(a), "v"(b));
  return d;
}
static __device__ __forceinline__ unsigned int pkh2(float lo, float hi) {
  return (unsigned int)f2h(lo) | ((unsigned int)f2h(hi) << 16);
}

// ---------------- K0: merged one-time weight prep ----------------
__global__ __launch_bounds__(256) void k_prep_all(const float* __restrict__ c1w,
                                                  const float* __restrict__ c2w,
                                                  const float* __restrict__ fcw,
                                                  const float* __restrict__ a1w1,
                                                  unsigned short* __restrict__ Wc1g,
                                                  unsigned short* __restrict__ Wg,
                                                  unsigned short* __restrict__ Wtfc,
                                                  unsigned short* __restrict__ Wt1) {
  int i = blockIdx.x * 256 + threadIdx.x;
  if (i < 6400) {
    int kh = i / 1280, r = i % 1280;
    int co = r / 40, q = r % 40;
    int kw = q >> 2, ci = q & 3;
    Wc1g[i] = f2h((co < 20 && ci < 3 && kw < 5) ? c1w[((co * 3 + ci) * 5 + kh) * 5 + kw] : 0.f);
    return;
  }
  i -= 6400;
  if (i < 38400) {
    int tap = i / 1536, r = i % 1536;
    int co = r / 24, ci = r % 24;
    Wg[i] = f2h((co < 50 && ci < 20) ? c2w[(co * 20 + ci) * 25 + tap] : 0.f);
    return;
  }
  i -= 38400;
  if (i < 409600) {
    int kt = i >> 14, r = i & 16383;
    int nn = r >> 5, kk = r & 31;
    int k = kt * 32 + kk;
    Wtfc[i] = f2h((nn < 500) ? fcw[k * 500 + nn] : 0.f);
    return;
  }
  i -= 409600;
  if (i < 65536) {
    int kt = i >> 12, r = i & 4095;
    int col = r >> 5, kk = r & 31;
    int k = kt * 32 + kk;
    Wt1[i] = f2h((k < 500) ? a1w1[k * 128 + col] : 0.f);
  }
}

// ---------------- K1: FUSED conv1+pool -> conv2+pool, 256 threads / 1 image ----------------
// 4 waves: conv1 chunks 3/2/2/2; conv2 m-tile per wave (A-reads 1/tap/wave, B 4/tap/wave).
__global__ __launch_bounds__(256, 2) void k_conv12(const float* __restrict__ x,
                                                   const unsigned short* __restrict__ Wc1g,
                                                   const float* __restrict__ cb1,   // conv1_b [20]
                                                   const unsigned short* __restrict__ Wg,
                                                   const float* __restrict__ cb2,   // conv2_b [50]
                                                   unsigned short* __restrict__ flat16) {
  __shared__ unsigned short xcl[3200];       // [800px][4ci] fp16 (tail 784..799 zero)
  __shared__ unsigned short h1s[3472];       // [144px][24co] + 16-short zero pad
  int tid = threadIdx.x;
  int n = blockIdx.x;
  int w = tid >> 6;                          // wave 0..3
  int lane = tid & 63;
  int r16 = lane & 15, g = lane >> 4;

  if (tid < 16) h1s[3456 + tid] = 0;         // conv2 g=3 junk A-read target: must be finite
  if (tid < 64) xcl[3136 + tid] = 0;         // conv1 kw-pad junk reads
  // stage x -> channel-last fp16 (load-all-then-write, static indices)
  {
    const float* xg = x + (size_t)n * 2352;
    float v0[4], v1[4], v2[4];
    #pragma unroll
    for (int i = 0; i < 4; ++i) {
      int p = tid + i * 256;
      if (p < 784) { v0[i] = xg[p]; v1[i] = xg[784 + p]; v2[i] = xg[1568 + p]; }
    }
    #pragma unroll
    for (int i = 0; i < 4; ++i) {
      int p = tid + i * 256;
      if (p < 784) {
        uint2 vv; vv.x = pkh2(v0[i], v1[i]); vv.y = (unsigned int)f2h(v2[i]);  // ci3 = 0
        *(uint2*)(xcl + 4 * p) = vv;
      }
    }
  }
  __syncthreads();

  // ================= conv1: static chunks per wave (3/2/2/2) =================
  {
    f16x8 bv[5][2];
    #pragma unroll
    for (int kh = 0; kh < 5; kh++) {
      bv[kh][0] = __builtin_bit_cast(f16x8, *(const uint4*)(Wc1g + (kh * 32 + r16) * 40 + 8 * g));
      bv[kh][1] = __builtin_bit_cast(f16x8, *(const uint4*)(Wc1g + (kh * 32 + 16 + r16) * 40 + 8 * g));
    }
    float bias0 = cb1[r16];
    float bias1 = (r16 < 4) ? cb1[16 + r16] : 0.f;
    unsigned int b2_0 = pkh2(bias0, bias0);
    unsigned int b2_1 = pkh2(bias1, bias1);
    int ay = (r16 >> 3), ax = (r16 & 7) + 2 * g;
    const unsigned short* xlane = xcl + (ay * 28 + ax) * 4;   // lane base (shorts)

    auto do_chunk = [&](const int chunk) {
      f32x4 acc[4][2];
      #pragma unroll
      for (int ti = 0; ti < 4; ti++) {
        acc[ti][0] = (f32x4){0.f, 0.f, 0.f, 0.f};
        acc[ti][1] = (f32x4){0.f, 0.f, 0.f, 0.f};
      }
      #pragma unroll
      for (int kh = 0; kh < 5; kh++) {
        #pragma unroll
        for (int ti = 0; ti < 4; ti++) {
          const int t = chunk * 4 + ti;
          const int ty = t / 3, tx = t - ty * 3;
          const unsigned short* p = xlane + ((2 * ty + kh) * 28 + 8 * tx) * 4;
          uint2 lo = *(const uint2*)p;
          uint2 hi = *(const uint2*)(p + 4);
          uint4 af; af.x = lo.x; af.y = lo.y; af.z = hi.x; af.w = hi.y;
          f16x8 av = __builtin_bit_cast(f16x8, af);
          acc[ti][0] = __builtin_amdgcn_mfma_f32_16x16x32_f16(av, bv[kh][0], acc[ti][0], 0, 0, 0);
          acc[ti][1] = __builtin_amdgcn_mfma_f32_16x16x32_f16(av, bv[kh][1], acc[ti][1], 0, 0, 0);
        }
      }
      // packed-f16 epilogue: pool + bias + relu -> h1s (stride 24)
      #pragma unroll
      for (int ti = 0; ti < 4; ti++) {
        const int t = chunk * 4 + ti;
        const int ty = t / 3, tx = t - ty * 3;
        #pragma unroll
        for (int nt = 0; nt < 2; nt++) {
          int co = 16 * nt + r16;
          f32x4 c = acc[ti][nt];
          unsigned int pk = pkh2(fmaxf(c[0], c[1]), fmaxf(c[2], c[3]));
          unsigned int other = (unsigned int)__shfl_xor((int)pk, 32);   // vertical pool partner
          unsigned int m2 = pk_max(pk, other);
          unsigned int r2 = pk_max(pk_add(m2, nt ? b2_1 : b2_0), 0u);   // +bias, relu
          if (g < 2 && co < 24) {
            int px0 = 4 * tx + 2 * g;
            unsigned short* o = h1s + (ty * 12 + px0) * 24 + co;
            o[0]  = (unsigned short)r2;
            o[24] = (unsigned short)(r2 >> 16);
          }
        }
      }
    };
    if      (w == 0) { do_chunk(0); do_chunk(4); do_chunk(8); }
    else if (w == 1) { do_chunk(1); do_chunk(5); }
    else if (w == 2) { do_chunk(2); do_chunk(6); }
    else             { do_chunk(3); do_chunk(7); }
  }
  __syncthreads();

  // ================= conv2: wave w owns m-tile w (all 4 n-tiles) =================
  {
    unsigned int cbp[4];
    cbp[0] = pkh2(cb2[r16], cb2[r16]);
    cbp[1] = pkh2(cb2[16 + r16], cb2[16 + r16]);
    cbp[2] = pkh2(cb2[32 + r16], cb2[32 + r16]);
    float cb3 = (r16 < 2) ? cb2[48 + r16] : 0.f;
    cbp[3] = pkh2(cb3, cb3);

    const unsigned short* Ab;
    {
      int posl = w * 16 + r16;
      int oy = posl >> 3, ox = posl & 7;
      Ab = h1s + (oy * 12 + ox) * 24 + 8 * g;
    }
    const unsigned short* Bb = Wg + r16 * 24 + 8 * g;   // + nt*384 + tap*1536

    f32x4 acc[4];
    #pragma unroll
    for (int nt = 0; nt < 4; nt++) acc[nt] = (f32x4){0.f, 0.f, 0.f, 0.f};

    uint4 FAa, FAb4[4], FBa, FBb4[4];
    auto lf = [&](uint4& A, uint4* B, const int tap) {
      const int kh = tap / 5, kw = tap % 5;             // folds: tap is literal
      const int dA = (kh * 12 + kw) * 24;
      const int dB = tap * 1536;
      #pragma unroll
      for (int nt = 0; nt < 4; nt++) {
        uint4 u = make_uint4(0, 0, 0, 0);
        if (g < 3) u = *(const uint4*)(Bb + dB + nt * 384);
        B[nt] = u;
      }
      A = *(const uint4*)(Ab + dA);
    };
    auto mma = [&](const uint4& A, const uint4* B) {
      f16x8 av = __builtin_bit_cast(f16x8, A);
      #pragma unroll
      for (int nt = 0; nt < 4; nt++) {
        acc[nt] = __builtin_amdgcn_mfma_f32_16x16x32_f16(
            av, __builtin_bit_cast(f16x8, B[nt]), acc[nt], 0, 0, 0);
      }
    };

    lf(FAa, FAb4, 0);
    #pragma unroll
    for (int tap = 0; tap < 25; tap += 2) {
      if (tap + 1 < 25) lf(FBa, FBb4, tap + 1);
      mma(FAa, FAb4);
      if (tap + 2 < 25) lf(FAa, FAb4, tap + 2);
      if (tap + 1 < 25) mma(FBa, FBb4);
    }

    #pragma unroll
    for (int nt = 0; nt < 4; nt++) {
      int co = 16 * nt + r16;
      f32x4 c = acc[nt];
      unsigned int pk = pkh2(fmaxf(c[0], c[1]), fmaxf(c[2], c[3]));
      unsigned int other = (unsigned int)__shfl_xor((int)pk, 32);
      unsigned int m2 = pk_max(pk, other);
      unsigned int r2 = pk_max(pk_add(m2, cbp[nt]), 0u);
      if (g < 2 && co < 50) {
        *(unsigned int*)(flat16 + ((size_t)n * 50 + co) * 16 + w * 4 + 2 * g) = r2;
      }
    }
  }
}

// ---------------- K3: FC 800->500 via fp16 MFMA ----------------
__global__ __launch_bounds__(256) void k_fc_mfma(const unsigned short* __restrict__ flat16,
                                                 const unsigned short* __restrict__ Wt,
                                                 const float* __restrict__ b,
                                                 float* __restrict__ H,
                                                 unsigned short* __restrict__ H16) {
  int tid = threadIdx.x;
  int wave = tid >> 6, lane = tid & 63;
  int r16 = lane & 15, g = lane >> 4;
  int bm = blockIdx.x & 15, bn = blockIdx.x >> 4;
  int m0 = bm * 256 + wave * 64;
  int n0 = bn * 32;

  f32x4 acc[4][2];
  #pragma unroll
  for (int mt = 0; mt < 4; mt++) {
    acc[mt][0] = (f32x4){0.f, 0.f, 0.f, 0.f};
    acc[mt][1] = (f32x4){0.f, 0.f, 0.f, 0.f};
  }

  const unsigned short* Abase = flat16 + (size_t)(m0 + r16) * 800 + 8 * g;
  const unsigned short* Bbase = Wt + (size_t)(n0 + r16) * 32 + 8 * g;

  for (int kt = 0; kt < 25; kt++) {
    uint4 bf0 = *(const uint4*)(Bbase + kt * 16384);
    uint4 bf1 = *(const uint4*)(Bbase + kt * 16384 + 512);
    f16x8 bv0 = __builtin_bit_cast(f16x8, bf0);
    f16x8 bv1 = __builtin_bit_cast(f16x8, bf1);
    #pragma unroll
    for (int mt = 0; mt < 4; mt++) {
      uint4 af = *(const uint4*)(Abase + mt * 12800 + kt * 32);
      f16x8 av = __builtin_bit_cast(f16x8, af);
      acc[mt][0] = __builtin_amdgcn_mfma_f32_16x16x32_f16(av, bv0, acc[mt][0], 0, 0, 0);
      acc[mt][1] = __builtin_amdgcn_mfma_f32_16x16x32_f16(av, bv1, acc[mt][1], 0, 0, 0);
    }
  }

  #pragma unroll
  for (int nt = 0; nt < 2; nt++) {
    int col = n0 + nt * 16 + r16;
    bool real = col < 500;
    float bias = real ? b[col] : 0.f;
    #pragma unroll
    for (int mt = 0; mt < 4; mt++) {
      #pragma unroll
      for (int j = 0; j < 4; j++) {
        int row = m0 + mt * 16 + 4 * g + j;
        float val = fmaxf(acc[mt][nt][j] + bias, 0.f);
        if (real) H[(size_t)row * 500 + col] = val;
        H16[(size_t)row * 512 + col] = f2h(val);
      }
    }
  }
}

// ---------------- K4: attn1 via fp16 MFMA + fused tanh/w2 reduction ----------------
__global__ __launch_bounds__(64) void k_attn1_mfma(const unsigned short* __restrict__ H16,
                                                   const unsigned short* __restrict__ Wt1,
                                                   const float* __restrict__ b1,   // [128]
                                                   const float* __restrict__ w2,   // [128]
                                                   const float* __restrict__ b2,   // [1]
                                                   float* __restrict__ a,
                                                   float* __restrict__ outA) {
  int lane = threadIdx.x;
  int r16 = lane & 15, g = lane >> 4;
  int m0 = blockIdx.x * 32;

  f32x4 acc[2][8];
  #pragma unroll
  for (int mt = 0; mt < 2; mt++)
    #pragma unroll
    for (int nt = 0; nt < 8; nt++) acc[mt][nt] = (f32x4){0.f, 0.f, 0.f, 0.f};

  const unsigned short* Abase = H16 + (size_t)(m0 + r16) * 512 + 8 * g;
  const unsigned short* Bbase = Wt1 + r16 * 32 + 8 * g;

  for (int kt = 0; kt < 16; kt++) {
    uint4 a0 = *(const uint4*)(Abase + kt * 32);
    uint4 a1 = *(const uint4*)(Abase + 16 * 512 + kt * 32);
    f16x8 av0 = __builtin_bit_cast(f16x8, a0);
    f16x8 av1 = __builtin_bit_cast(f16x8, a1);
    #pragma unroll
    for (int nt = 0; nt < 8; nt++) {
      uint4 bf = *(const uint4*)(Bbase + kt * 4096 + nt * 512);
      f16x8 bv = __builtin_bit_cast(f16x8, bf);
      acc[0][nt] = __builtin_amdgcn_mfma_f32_16x16x32_f16(av0, bv, acc[0][nt], 0, 0, 0);
      acc[1][nt] = __builtin_amdgcn_mfma_f32_16x16x32_f16(av1, bv, acc[1][nt], 0, 0, 0);
    }
  }

  float b1v[8], w2v[8];
  #pragma unroll
  for (int nt = 0; nt < 8; nt++) {
    int col = nt * 16 + r16;
    b1v[nt] = b1[col];
    w2v[nt] = w2[col];
  }
  float bb2 = b2[0];

  #pragma unroll
  for (int mt = 0; mt < 2; mt++) {
    float part[4];
    #pragma unroll
    for (int j = 0; j < 4; j++) {
      float s = 0.f;
      #pragma unroll
      for (int nt = 0; nt < 8; nt++)
        s += tanhf(acc[mt][nt][j] + b1v[nt]) * w2v[nt];
      part[j] = s;
    }
    #pragma unroll
    for (int off = 1; off < 16; off <<= 1) {
      #pragma unroll
      for (int j = 0; j < 4; j++) part[j] += __shfl_xor(part[j], off);
    }
    if (r16 == 0) {
      #pragma unroll
      for (int j = 0; j < 4; j++) {
        int row = m0 + mt * 16 + 4 * g + j;
        float val = part[j] + bb2;
        a[row] = val;
        outA[row] = val;
      }
    }
  }
}

// ---------------- K5: FUSED per-segment softmax pooling + bag-attn logit ----------------
__global__ __launch_bounds__(512) void k_segbatt(const float* __restrict__ a,
                                                 const float* __restrict__ H,
                                                 const int* __restrict__ idx,
                                                 const float* __restrict__ w1,   // a2_w1 [500,128]
                                                 const float* __restrict__ b1,   // a2_b1 [128]
                                                 const float* __restrict__ w2,   // a2_w2 [128]
                                                 const float* __restrict__ b2,   // a2_b2 [1]
                                                 float* __restrict__ instf,
                                                 float* __restrict__ batt) {
  __shared__ float fs[500];
  __shared__ float part[512];
  __shared__ float pool[4][500];
  __shared__ float red[8];
  __shared__ float sval;
  int s = blockIdx.x, tid = threadIdx.x;
  int i0 = idx[s], i1 = idx[s + 1];

  float mx = -INFINITY;
  for (int i = i0 + tid; i < i1; i += 512) mx = fmaxf(mx, a[i]);
  #pragma unroll
  for (int off = 32; off > 0; off >>= 1) mx = fmaxf(mx, __shfl_down(mx, off));
  if ((tid & 63) == 0) red[tid >> 6] = mx;
  __syncthreads();
  if (tid == 0) {
    float m2 = red[0];
    #pragma unroll
    for (int j = 1; j < 8; j++) m2 = fmaxf(m2, red[j]);
    sval = m2;
  }
  __syncthreads();
  float m = sval;
  float sm = 0.f;
  for (int i = i0 + tid; i < i1; i += 512) sm += expf(a[i] - m);
  #pragma unroll
  for (int off = 32; off > 0; off >>= 1) sm += __shfl_down(sm, off);
  if ((tid & 63) == 0) red[tid >> 6] = sm;
  __syncthreads();
  if (tid == 0) {
    float t2 = 0.f;
    #pragma unroll
    for (int j = 0; j < 8; j++) t2 += red[j];
    sval = t2;
  }
  __syncthreads();
  float inv = 1.f / sval;
  {
    int q = tid >> 7;             // 0..3
    int t = tid & 127;
    int len = i1 - i0;
    int lo = i0 + (len * q) / 4;
    int hi = i0 + (len * (q + 1)) / 4;
    if (t < 125) {
      float a0 = 0.f, a1 = 0.f, a2 = 0.f, a3 = 0.f;
      for (int i = lo; i < hi; i++) {
        float e = expf(a[i] - m) * inv;
        const float* Hr = H + (size_t)i * 500 + t;
        a0 += e * Hr[0];
        a1 += e * Hr[125];
        a2 += e * Hr[250];
        a3 += e * Hr[375];
      }
      pool[q][t]       = a0;
      pool[q][t + 125] = a1;
      pool[q][t + 250] = a2;
      pool[q][t + 375] = a3;
    }
  }
  __syncthreads();
  if (tid < 500) {
    float v = pool[0][tid] + pool[1][tid] + pool[2][tid] + pool[3][tid];
    instf[s * 500 + tid] = v;
    fs[tid] = v;
  }
  __syncthreads();
  int c = tid & 127, q = tid >> 7;
  float t = 0.f;
  int k0 = q * 125;
  #pragma unroll 5
  for (int k = k0; k < k0 + 125; k++) t += fs[k] * w1[k * 128 + c];
  part[tid] = t;
  __syncthreads();
  if (tid < 128) {
    float tt = part[tid] + part[tid + 128] + part[tid + 256] + part[tid + 384] + b1[tid];
    float v = tanhf(tt) * w2[tid];
    #pragma unroll
    for (int off = 32; off > 0; off >>= 1) v += __shfl_down(v, off);
    if ((tid & 63) == 0) red[tid >> 6] = v;
  }
  __syncthreads();
  if (tid == 0) batt[s] = red[0] + red[1] + b2[0];
}

// ---------------- K7: softmax(b_att) -> bag feature -> classifier ----------------
__global__ __launch_bounds__(256) void k_final(const float* __restrict__ batt,
                                               const float* __restrict__ instf,
                                               const float* __restrict__ clfw,
                                               const float* __restrict__ clfb,
                                               float* __restrict__ out) {
  __shared__ float Bsh[64];
  __shared__ float red[4];
  int tid = threadIdx.x;
  if (tid < 64) {
    float v = batt[tid];
    float mx = v;
    #pragma unroll
    for (int off = 32; off > 0; off >>= 1) mx = fmaxf(mx, __shfl_xor(mx, off));
    float e = expf(v - mx);
    float smv = e;
    #pragma unroll
    for (int off = 32; off > 0; off >>= 1) smv += __shfl_xor(smv, off);
    Bsh[tid] = e / smv;
  }
  __syncthreads();
  float part = 0.f;
  if (tid < 250) {
    float bag0 = 0.f, bag1 = 0.f;
    #pragma unroll 4
    for (int s2 = 0; s2 < 64; s2++) {
      float Bv = Bsh[s2];
      bag0 += Bv * instf[s2 * 500 + tid];
      bag1 += Bv * instf[s2 * 500 + tid + 250];
    }
    part = bag0 * clfw[tid] + bag1 * clfw[tid + 250];
  }
  #pragma unroll
  for (int off = 32; off > 0; off >>= 1) part += __shfl_down(part, off);
  if ((tid & 63) == 0) red[tid >> 6] = part;
  __syncthreads();
  if (tid == 0) {
    float z = red[0] + red[1] + red[2] + red[3] + clfb[0];
    out[0] = 1.f / (1.f + expf(-z));
    out[1] = (z >= 0.f) ? 1.f : 0.f;
  }
}

extern "C" void kernel_launch(void* const* d_in, const int* in_sizes, int n_in,
                              void* d_out, int out_size, void* d_ws, size_t ws_size,
                              hipStream_t stream) {
  const float* x       = (const float*)d_in[0];
  const int*   idx     = (const int*)d_in[1];
  const float* conv1_w = (const float*)d_in[2];
  const float* conv1_b = (const float*)d_in[3];
  const float* conv2_w = (const float*)d_in[4];
  const float* conv2_b = (const float*)d_in[5];
  const float* fc_w    = (const float*)d_in[6];
  const float* fc_b    = (const float*)d_in[7];
  const float* a1_w1   = (const float*)d_in[8];
  const float* a1_b1   = (const float*)d_in[9];
  const float* a1_w2   = (const float*)d_in[10];
  const float* a1_b2   = (const float*)d_in[11];
  const float* a2_w1   = (const float*)d_in[12];
  const float* a2_b1   = (const float*)d_in[13];
  const float* a2_w2   = (const float*)d_in[14];
  const float* a2_b2   = (const float*)d_in[15];
  const float* clf_w   = (const float*)d_in[16];
  const float* clf_b   = (const float*)d_in[17];
  float* out = (float*)d_out;

  int N = in_sizes[0] / 2352;     // 4096
  int S = in_sizes[1] - 1;        // 64

  // workspace layout
  float* wsf   = (float*)d_ws;
  float* H     = wsf;                          // N*500 f32
  float* a     = H + (size_t)N * 500;          // N
  float* instf = a + N;                        // S*500
  float* batt  = instf + (size_t)S * 500;      // S
  unsigned short* Wg    = (unsigned short*)(batt + S + 8);   // 38400
  unsigned short* Wc1g  = Wg + 38400;                        // 6400
  unsigned short* Wtfc  = Wc1g + 6400;                       // 409600
  unsigned short* Wt1   = Wtfc + 409600;                     // 65536
  unsigned short* flat16= Wt1 + 65536;                       // N*800 fp16
  unsigned short* H16   = flat16 + (size_t)N * 800;          // N*512 fp16

  k_prep_all<<<2031, 256, 0, stream>>>(conv1_w, conv2_w, fc_w, a1_w1, Wc1g, Wg, Wtfc, Wt1);
  k_conv12<<<N, 256, 0, stream>>>(x, Wc1g, conv1_b, Wg, conv2_b, flat16);
  k_fc_mfma<<<256, 256, 0, stream>>>(flat16, Wtfc, fc_b, H, H16);
  k_attn1_mfma<<<N / 32, 64, 0, stream>>>(H16, Wt1, a1_b1, a1_w2, a1_b2, a, out + 2);
  k_segbatt<<<S, 512, 0, stream>>>(a, H, idx, a2_w1, a2_b1, a2_w2, a2_b2, instf, batt);
  k_final<<<1, 256, 0, stream>>>(batt, instf, clf_w, clf_b, out);
}

// Round 19
// 126.249 us; speedup vs baseline: 1.1468x; 1.1468x over previous
//
#include <hip/hip_runtime.h>
#include <math.h>

typedef _Float16 f16x8 __attribute__((ext_vector_type(8)));
typedef float    f32x4 __attribute__((ext_vector_type(4)));

static __device__ __forceinline__ unsigned short f2h(float f) {
  _Float16 h = (_Float16)f;                       // RNE
  return __builtin_bit_cast(unsigned short, h);
}
// packed f16 helpers (VOP3P)
static __device__ __forceinline__ unsigned int pk_max(unsigned int a, unsigned int b) {
  unsigned int d;
  asm("v_pk_max_f16 %0, %1, %2" : "=v"(d) : "v"(a), "v"(b));
  return d;
}
static __device__ __forceinline__ unsigned int pk_add(unsigned int a, unsigned int b) {
  unsigned int d;
  asm("v_pk_add_f16 %0, %1, %2" : "=v"(d) : "v"(a), "v"(b));
  return d;
}
static __device__ __forceinline__ unsigned int pkh2(float lo, float hi) {
  return (unsigned int)f2h(lo) | ((unsigned int)f2h(hi) << 16);
}

// ---------------- K0: merged one-time weight prep ----------------
__global__ __launch_bounds__(256) void k_prep_all(const float* __restrict__ c1w,
                                                  const float* __restrict__ c2w,
                                                  const float* __restrict__ fcw,
                                                  const float* __restrict__ a1w1,
                                                  unsigned short* __restrict__ Wc1g,
                                                  unsigned short* __restrict__ Wg,
                                                  unsigned short* __restrict__ Wtfc,
                                                  unsigned short* __restrict__ Wt1) {
  int i = blockIdx.x * 256 + threadIdx.x;
  if (i < 6400) {
    int kh = i / 1280, r = i % 1280;
    int co = r / 40, q = r % 40;
    int kw = q >> 2, ci = q & 3;
    Wc1g[i] = f2h((co < 20 && ci < 3 && kw < 5) ? c1w[((co * 3 + ci) * 5 + kh) * 5 + kw] : 0.f);
    return;
  }
  i -= 6400;
  if (i < 38400) {
    int tap = i / 1536, r = i % 1536;
    int co = r / 24, ci = r % 24;
    Wg[i] = f2h((co < 50 && ci < 20) ? c2w[(co * 20 + ci) * 25 + tap] : 0.f);
    return;
  }
  i -= 38400;
  if (i < 409600) {
    int kt = i >> 14, r = i & 16383;
    int nn = r >> 5, kk = r & 31;
    int k = kt * 32 + kk;
    Wtfc[i] = f2h((nn < 500) ? fcw[k * 500 + nn] : 0.f);
    return;
  }
  i -= 409600;
  if (i < 65536) {
    int kt = i >> 12, r = i & 4095;
    int col = r >> 5, kk = r & 31;
    int k = kt * 32 + kk;
    Wt1[i] = f2h((k < 500) ? a1w1[k * 128 + col] : 0.f);
  }
}

// ---------------- K1: FUSED conv1+pool -> conv2+pool, 128 threads / 1 image (R13 best) ----------------
__global__ __launch_bounds__(128, 2) void k_conv12(const float* __restrict__ x,
                                                   const unsigned short* __restrict__ Wc1g,
                                                   const float* __restrict__ cb1,   // conv1_b [20]
                                                   const unsigned short* __restrict__ Wg,
                                                   const float* __restrict__ cb2,   // conv2_b [50]
                                                   unsigned short* __restrict__ flat16) {
  __shared__ unsigned short xcl[3200];       // [800px][4ci] fp16 (tail 784..799 zero)
  __shared__ unsigned short h1s[3472];       // [144px][24co] + 16-short zero pad
  int tid = threadIdx.x;
  int n = blockIdx.x;
  int w = tid >> 6;                          // wave 0/1
  int lane = tid & 63;
  int r16 = lane & 15, g = lane >> 4;

  if (tid < 16) h1s[3456 + tid] = 0;         // conv2 g=3 junk A-read target: must be finite
  if (tid < 64) xcl[3136 + tid] = 0;         // conv1 kw-pad junk reads
  // stage x -> channel-last fp16 (load-all-then-write, static indices)
  {
    const float* xg = x + (size_t)n * 2352;
    float v0[7], v1[7], v2[7];
    #pragma unroll
    for (int i = 0; i < 7; ++i) {
      int p = tid + i * 128;
      if (p < 784) { v0[i] = xg[p]; v1[i] = xg[784 + p]; v2[i] = xg[1568 + p]; }
    }
    #pragma unroll
    for (int i = 0; i < 7; ++i) {
      int p = tid + i * 128;
      if (p < 784) {
        uint2 vv; vv.x = pkh2(v0[i], v1[i]); vv.y = (unsigned int)f2h(v2[i]);  // ci3 = 0
        *(uint2*)(xcl + 4 * p) = vv;
      }
    }
  }
  __syncthreads();

  // ================= conv1: static chunks per wave =================
  {
    f16x8 bv[5][2];
    #pragma unroll
    for (int kh = 0; kh < 5; kh++) {
      bv[kh][0] = __builtin_bit_cast(f16x8, *(const uint4*)(Wc1g + (kh * 32 + r16) * 40 + 8 * g));
      bv[kh][1] = __builtin_bit_cast(f16x8, *(const uint4*)(Wc1g + (kh * 32 + 16 + r16) * 40 + 8 * g));
    }
    float bias0 = cb1[r16];
    float bias1 = (r16 < 4) ? cb1[16 + r16] : 0.f;
    unsigned int b2_0 = pkh2(bias0, bias0);
    unsigned int b2_1 = pkh2(bias1, bias1);
    int ay = (r16 >> 3), ax = (r16 & 7) + 2 * g;
    const unsigned short* xlane = xcl + (ay * 28 + ax) * 4;   // lane base (shorts)

    auto do_chunk = [&](const int chunk) {
      f32x4 acc[4][2];
      #pragma unroll
      for (int ti = 0; ti < 4; ti++) {
        acc[ti][0] = (f32x4){0.f, 0.f, 0.f, 0.f};
        acc[ti][1] = (f32x4){0.f, 0.f, 0.f, 0.f};
      }
      #pragma unroll
      for (int kh = 0; kh < 5; kh++) {
        #pragma unroll
        for (int ti = 0; ti < 4; ti++) {
          const int t = chunk * 4 + ti;
          const int ty = t / 3, tx = t - ty * 3;
          const unsigned short* p = xlane + ((2 * ty + kh) * 28 + 8 * tx) * 4;
          uint2 lo = *(const uint2*)p;
          uint2 hi = *(const uint2*)(p + 4);
          uint4 af; af.x = lo.x; af.y = lo.y; af.z = hi.x; af.w = hi.y;
          f16x8 av = __builtin_bit_cast(f16x8, af);
          acc[ti][0] = __builtin_amdgcn_mfma_f32_16x16x32_f16(av, bv[kh][0], acc[ti][0], 0, 0, 0);
          acc[ti][1] = __builtin_amdgcn_mfma_f32_16x16x32_f16(av, bv[kh][1], acc[ti][1], 0, 0, 0);
        }
      }
      // packed-f16 epilogue: pool + bias + relu -> h1s (stride 24)
      #pragma unroll
      for (int ti = 0; ti < 4; ti++) {
        const int t = chunk * 4 + ti;
        const int ty = t / 3, tx = t - ty * 3;
        #pragma unroll
        for (int nt = 0; nt < 2; nt++) {
          int co = 16 * nt + r16;
          f32x4 c = acc[ti][nt];
          unsigned int pk = pkh2(fmaxf(c[0], c[1]), fmaxf(c[2], c[3]));
          unsigned int other = (unsigned int)__shfl_xor((int)pk, 32);   // vertical pool partner
          unsigned int m2 = pk_max(pk, other);
          unsigned int r2 = pk_max(pk_add(m2, nt ? b2_1 : b2_0), 0u);   // +bias, relu
          if (g < 2 && co < 24) {
            int px0 = 4 * tx + 2 * g;
            unsigned short* o = h1s + (ty * 12 + px0) * 24 + co;
            o[0]  = (unsigned short)r2;
            o[24] = (unsigned short)(r2 >> 16);
          }
        }
      }
    };
    if (w == 0) { do_chunk(0); do_chunk(2); do_chunk(4); do_chunk(6); do_chunk(8); }
    else        { do_chunk(1); do_chunk(3); do_chunk(5); do_chunk(7); }
  }
  __syncthreads();

  // ================= conv2: wave w takes m-tiles 2w, 2w+1 =================
  {
    unsigned int cbp[4];
    cbp[0] = pkh2(cb2[r16], cb2[r16]);
    cbp[1] = pkh2(cb2[16 + r16], cb2[16 + r16]);
    cbp[2] = pkh2(cb2[32 + r16], cb2[32 + r16]);
    float cb3 = (r16 < 2) ? cb2[48 + r16] : 0.f;
    cbp[3] = pkh2(cb3, cb3);

    const unsigned short* Ab[2];
    #pragma unroll
    for (int mtp = 0; mtp < 2; mtp++) {
      int posl = (2 * w + mtp) * 16 + r16;
      int oy = posl >> 3, ox = posl & 7;
      Ab[mtp] = h1s + (oy * 12 + ox) * 24 + 8 * g;
    }
    const unsigned short* Bb = Wg + r16 * 24 + 8 * g;   // + nt*384 + tap*1536

    f32x4 acc[2][4];
    #pragma unroll
    for (int mt = 0; mt < 2; mt++)
      #pragma unroll
      for (int nt = 0; nt < 4; nt++) acc[mt][nt] = (f32x4){0.f, 0.f, 0.f, 0.f};

    uint4 FAa[2], FAb[4], FBa[2], FBb[4];
    auto lf = [&](uint4* A, uint4* B, const int tap) {
      const int kh = tap / 5, kw = tap % 5;             // folds: tap is literal
      const int dA = (kh * 12 + kw) * 24;
      const int dB = tap * 1536;
      #pragma unroll
      for (int nt = 0; nt < 4; nt++) {
        uint4 u = make_uint4(0, 0, 0, 0);
        if (g < 3) u = *(const uint4*)(Bb + dB + nt * 384);
        B[nt] = u;
      }
      A[0] = *(const uint4*)(Ab[0] + dA);
      A[1] = *(const uint4*)(Ab[1] + dA);
    };
    auto mma = [&](const uint4* A, const uint4* B) {
      #pragma unroll
      for (int mt = 0; mt < 2; mt++) {
        f16x8 av = __builtin_bit_cast(f16x8, A[mt]);
        #pragma unroll
        for (int nt = 0; nt < 4; nt++) {
          acc[mt][nt] = __builtin_amdgcn_mfma_f32_16x16x32_f16(
              av, __builtin_bit_cast(f16x8, B[nt]), acc[mt][nt], 0, 0, 0);
        }
      }
    };

    lf(FAa, FAb, 0);
    #pragma unroll
    for (int tap = 0; tap < 25; tap += 2) {
      if (tap + 1 < 25) lf(FBa, FBb, tap + 1);
      mma(FAa, FAb);
      if (tap + 2 < 25) lf(FAa, FAb, tap + 2);
      if (tap + 1 < 25) mma(FBa, FBb);
    }

    #pragma unroll
    for (int mtp = 0; mtp < 2; mtp++) {
      int py = 2 * w + mtp;
      #pragma unroll
      for (int nt = 0; nt < 4; nt++) {
        int co = 16 * nt + r16;
        f32x4 c = acc[mtp][nt];
        unsigned int pk = pkh2(fmaxf(c[0], c[1]), fmaxf(c[2], c[3]));
        unsigned int other = (unsigned int)__shfl_xor((int)pk, 32);
        unsigned int m2 = pk_max(pk, other);
        unsigned int r2 = pk_max(pk_add(m2, cbp[nt]), 0u);
        if (g < 2 && co < 50) {
          *(unsigned int*)(flat16 + ((size_t)n * 50 + co) * 16 + py * 4 + 2 * g) = r2;
        }
      }
    }
  }
}

// ---------------- K3: FC 800->500 via fp16 MFMA (512 blocks: 2/CU, M=128/block) ----------------
__global__ __launch_bounds__(256) void k_fc_mfma(const unsigned short* __restrict__ flat16,
                                                 const unsigned short* __restrict__ Wt,
                                                 const float* __restrict__ b,
                                                 float* __restrict__ H,
                                                 unsigned short* __restrict__ H16) {
  int tid = threadIdx.x;
  int wave = tid >> 6, lane = tid & 63;
  int r16 = lane & 15, g = lane >> 4;
  int bm = blockIdx.x >> 4, bn = blockIdx.x & 15;   // bm 0..31, bn 0..15
  int m0 = bm * 128 + wave * 32;
  int n0 = bn * 32;

  f32x4 acc[2][2];
  #pragma unroll
  for (int mt = 0; mt < 2; mt++) {
    acc[mt][0] = (f32x4){0.f, 0.f, 0.f, 0.f};
    acc[mt][1] = (f32x4){0.f, 0.f, 0.f, 0.f};
  }

  const unsigned short* Abase = flat16 + (size_t)(m0 + r16) * 800 + 8 * g;
  const unsigned short* Bbase = Wt + (size_t)(n0 + r16) * 32 + 8 * g;

  for (int kt = 0; kt < 25; kt++) {
    uint4 bf0 = *(const uint4*)(Bbase + kt * 16384);
    uint4 bf1 = *(const uint4*)(Bbase + kt * 16384 + 512);
    f16x8 bv0 = __builtin_bit_cast(f16x8, bf0);
    f16x8 bv1 = __builtin_bit_cast(f16x8, bf1);
    #pragma unroll
    for (int mt = 0; mt < 2; mt++) {
      uint4 af = *(const uint4*)(Abase + mt * 12800 + kt * 32);
      f16x8 av = __builtin_bit_cast(f16x8, af);
      acc[mt][0] = __builtin_amdgcn_mfma_f32_16x16x32_f16(av, bv0, acc[mt][0], 0, 0, 0);
      acc[mt][1] = __builtin_amdgcn_mfma_f32_16x16x32_f16(av, bv1, acc[mt][1], 0, 0, 0);
    }
  }

  #pragma unroll
  for (int nt = 0; nt < 2; nt++) {
    int col = n0 + nt * 16 + r16;
    bool real = col < 500;
    float bias = real ? b[col] : 0.f;
    #pragma unroll
    for (int mt = 0; mt < 2; mt++) {
      #pragma unroll
      for (int j = 0; j < 4; j++) {
        int row = m0 + mt * 16 + 4 * g + j;
        float val = fmaxf(acc[mt][nt][j] + bias, 0.f);
        if (real) H[(size_t)row * 500 + col] = val;
        H16[(size_t)row * 512 + col] = f2h(val);
      }
    }
  }
}

// ---------------- K4: attn1 via fp16 MFMA, 16 rows / block (full CU coverage) ----------------
__global__ __launch_bounds__(64) void k_attn1_mfma(const unsigned short* __restrict__ H16,
                                                   const unsigned short* __restrict__ Wt1,
                                                   const float* __restrict__ b1,   // [128]
                                                   const float* __restrict__ w2,   // [128]
                                                   const float* __restrict__ b2,   // [1]
                                                   float* __restrict__ a,
                                                   float* __restrict__ outA) {
  int lane = threadIdx.x;
  int r16 = lane & 15, g = lane >> 4;
  int m0 = blockIdx.x * 16;

  f32x4 acc[8];
  #pragma unroll
  for (int nt = 0; nt < 8; nt++) acc[nt] = (f32x4){0.f, 0.f, 0.f, 0.f};

  const unsigned short* Abase = H16 + (size_t)(m0 + r16) * 512 + 8 * g;
  const unsigned short* Bbase = Wt1 + r16 * 32 + 8 * g;

  for (int kt = 0; kt < 16; kt++) {
    uint4 a0 = *(const uint4*)(Abase + kt * 32);
    f16x8 av0 = __builtin_bit_cast(f16x8, a0);
    #pragma unroll
    for (int nt = 0; nt < 8; nt++) {
      uint4 bf = *(const uint4*)(Bbase + kt * 4096 + nt * 512);
      f16x8 bv = __builtin_bit_cast(f16x8, bf);
      acc[nt] = __builtin_amdgcn_mfma_f32_16x16x32_f16(av0, bv, acc[nt], 0, 0, 0);
    }
  }

  float b1v[8], w2v[8];
  #pragma unroll
  for (int nt = 0; nt < 8; nt++) {
    int col = nt * 16 + r16;
    b1v[nt] = b1[col];
    w2v[nt] = w2[col];
  }
  float bb2 = b2[0];

  float part[4];
  #pragma unroll
  for (int j = 0; j < 4; j++) {
    float s = 0.f;
    #pragma unroll
    for (int nt = 0; nt < 8; nt++)
      s += tanhf(acc[nt][j] + b1v[nt]) * w2v[nt];
    part[j] = s;
  }
  #pragma unroll
  for (int off = 1; off < 16; off <<= 1) {
    #pragma unroll
    for (int j = 0; j < 4; j++) part[j] += __shfl_xor(part[j], off);
  }
  if (r16 == 0) {
    #pragma unroll
    for (int j = 0; j < 4; j++) {
      int row = m0 + 4 * g + j;
      float val = part[j] + bb2;
      a[row] = val;
      outA[row] = val;
    }
  }
}

// ---------------- K5: FUSED per-segment softmax pooling + bag-attn logit ----------------
__global__ __launch_bounds__(512) void k_segbatt(const float* __restrict__ a,
                                                 const float* __restrict__ H,
                                                 const int* __restrict__ idx,
                                                 const float* __restrict__ w1,   // a2_w1 [500,128]
                                                 const float* __restrict__ b1,   // a2_b1 [128]
                                                 const float* __restrict__ w2,   // a2_w2 [128]
                                                 const float* __restrict__ b2,   // a2_b2 [1]
                                                 float* __restrict__ instf,
                                                 float* __restrict__ batt) {
  __shared__ float fs[500];
  __shared__ float part[512];
  __shared__ float pool[4][500];
  __shared__ float red[8];
  __shared__ float sval;
  int s = blockIdx.x, tid = threadIdx.x;
  int i0 = idx[s], i1 = idx[s + 1];

  float mx = -INFINITY;
  for (int i = i0 + tid; i < i1; i += 512) mx = fmaxf(mx, a[i]);
  #pragma unroll
  for (int off = 32; off > 0; off >>= 1) mx = fmaxf(mx, __shfl_down(mx, off));
  if ((tid & 63) == 0) red[tid >> 6] = mx;
  __syncthreads();
  if (tid == 0) {
    float m2 = red[0];
    #pragma unroll
    for (int j = 1; j < 8; j++) m2 = fmaxf(m2, red[j]);
    sval = m2;
  }
  __syncthreads();
  float m = sval;
  float sm = 0.f;
  for (int i = i0 + tid; i < i1; i += 512) sm += expf(a[i] - m);
  #pragma unroll
  for (int off = 32; off > 0; off >>= 1) sm += __shfl_down(sm, off);
  if ((tid & 63) == 0) red[tid >> 6] = sm;
  __syncthreads();
  if (tid == 0) {
    float t2 = 0.f;
    #pragma unroll
    for (int j = 0; j < 8; j++) t2 += red[j];
    sval = t2;
  }
  __syncthreads();
  float inv = 1.f / sval;
  {
    int q = tid >> 7;             // 0..3
    int t = tid & 127;
    int len = i1 - i0;
    int lo = i0 + (len * q) / 4;
    int hi = i0 + (len * (q + 1)) / 4;
    if (t < 125) {
      float a0 = 0.f, a1 = 0.f, a2 = 0.f, a3 = 0.f;
      for (int i = lo; i < hi; i++) {
        float e = expf(a[i] - m) * inv;
        const float* Hr = H + (size_t)i * 500 + t;
        a0 += e * Hr[0];
        a1 += e * Hr[125];
        a2 += e * Hr[250];
        a3 += e * Hr[375];
      }
      pool[q][t]       = a0;
      pool[q][t + 125] = a1;
      pool[q][t + 250] = a2;
      pool[q][t + 375] = a3;
    }
  }
  __syncthreads();
  if (tid < 500) {
    float v = pool[0][tid] + pool[1][tid] + pool[2][tid] + pool[3][tid];
    instf[s * 500 + tid] = v;
    fs[tid] = v;
  }
  __syncthreads();
  int c = tid & 127, q = tid >> 7;
  float t = 0.f;
  int k0 = q * 125;
  #pragma unroll 5
  for (int k = k0; k < k0 + 125; k++) t += fs[k] * w1[k * 128 + c];
  part[tid] = t;
  __syncthreads();
  if (tid < 128) {
    float tt = part[tid] + part[tid + 128] + part[tid + 256] + part[tid + 384] + b1[tid];
    float v = tanhf(tt) * w2[tid];
    #pragma unroll
    for (int off = 32; off > 0; off >>= 1) v += __shfl_down(v, off);
    if ((tid & 63) == 0) red[tid >> 6] = v;
  }
  __syncthreads();
  if (tid == 0) batt[s] = red[0] + red[1] + b2[0];
}

// ---------------- K7: softmax(b_att) -> bag feature -> classifier ----------------
__global__ __launch_bounds__(256) void k_final(const float* __restrict__ batt,
                                               const float* __restrict__ instf,
                                               const float* __restrict__ clfw,
                                               const float* __restrict__ clfb,
                                               float* __restrict__ out) {
  __shared__ float Bsh[64];
  __shared__ float red[4];
  int tid = threadIdx.x;
  if (tid < 64) {
    float v = batt[tid];
    float mx = v;
    #pragma unroll
    for (int off = 32; off > 0; off >>= 1) mx = fmaxf(mx, __shfl_xor(mx, off));
    float e = expf(v - mx);
    float smv = e;
    #pragma unroll
    for (int off = 32; off > 0; off >>= 1) smv += __shfl_xor(smv, off);
    Bsh[tid] = e / smv;
  }
  __syncthreads();
  float part = 0.f;
  if (tid < 250) {
    float bag0 = 0.f, bag1 = 0.f;
    #pragma unroll 4
    for (int s2 = 0; s2 < 64; s2++) {
      float Bv = Bsh[s2];
      bag0 += Bv * instf[s2 * 500 + tid];
      bag1 += Bv * instf[s2 * 500 + tid + 250];
    }
    part = bag0 * clfw[tid] + bag1 * clfw[tid + 250];
  }
  #pragma unroll
  for (int off = 32; off > 0; off >>= 1) part += __shfl_down(part, off);
  if ((tid & 63) == 0) red[tid >> 6] = part;
  __syncthreads();
  if (tid == 0) {
    float z = red[0] + red[1] + red[2] + red[3] + clfb[0];
    out[0] = 1.f / (1.f + expf(-z));
    out[1] = (z >= 0.f) ? 1.f : 0.f;
  }
}

extern "C" void kernel_launch(void* const* d_in, const int* in_sizes, int n_in,
                              void* d_out, int out_size, void* d_ws, size_t ws_size,
                              hipStream_t stream) {
  const float* x       = (const float*)d_in[0];
  const int*   idx     = (const int*)d_in[1];
  const float* conv1_w = (const float*)d_in[2];
  const float* conv1_b = (const float*)d_in[3];
  const float* conv2_w = (const float*)d_in[4];
  const float* conv2_b = (const float*)d_in[5];
  const float* fc_w    = (const float*)d_in[6];
  const float* fc_b    = (const float*)d_in[7];
  const float* a1_w1   = (const float*)d_in[8];
  const float* a1_b1   = (const float*)d_in[9];
  const float* a1_w2   = (const float*)d_in[10];
  const float* a1_b2   = (const float*)d_in[11];
  const float* a2_w1   = (const float*)d_in[12];
  const float* a2_b1   = (const float*)d_in[13];
  const float* a2_w2   = (const float*)d_in[14];
  const float* a2_b2   = (const float*)d_in[15];
  const float* clf_w   = (const float*)d_in[16];
  const float* clf_b   = (const float*)d_in[17];
  float* out = (float*)d_out;

  int N = in_sizes[0] / 2352;     // 4096
  int S = in_sizes[1] - 1;        // 64

  // workspace layout
  float* wsf   = (float*)d_ws;
  float* H     = wsf;                          // N*500 f32
  float* a     = H + (size_t)N * 500;          // N
  float* instf = a + N;                        // S*500
  float* batt  = instf + (size_t)S * 500;      // S
  unsigned short* Wg    = (unsigned short*)(batt + S + 8);   // 38400
  unsigned short* Wc1g  = Wg + 38400;                        // 6400
  unsigned short* Wtfc  = Wc1g + 6400;                       // 409600
  unsigned short* Wt1   = Wtfc + 409600;                     // 65536
  unsigned short* flat16= Wt1 + 65536;                       // N*800 fp16
  unsigned short* H16   = flat16 + (size_t)N * 800;          // N*512 fp16

  k_prep_all<<<2031, 256, 0, stream>>>(conv1_w, conv2_w, fc_w, a1_w1, Wc1g, Wg, Wtfc, Wt1);
  k_conv12<<<N, 128, 0, stream>>>(x, Wc1g, conv1_b, Wg, conv2_b, flat16);
  k_fc_mfma<<<512, 256, 0, stream>>>(flat16, Wtfc, fc_b, H, H16);
  k_attn1_mfma<<<N / 16, 64, 0, stream>>>(H16, Wt1, a1_b1, a1_w2, a1_b2, a, out + 2);
  k_segbatt<<<S, 512, 0, stream>>>(a, H, idx, a2_w1, a2_b1, a2_w2, a2_b2, instf, batt);
  k_final<<<1, 256, 0, stream>>>(batt, instf, clf_w, clf_b, out);
}